// Round 3
// baseline (398.664 us; speedup 1.0000x reference)
//
#include <hip/hip_runtime.h>
#include <math.h>

// Problem constants (fixed by setup_inputs):
//   x: (512, 512, 9, 9) fp32, theta: (4,) fp32, lam: (4,) fp32
//   out: (4*512, 512, 9, 9) fp32 = gabor[g,h,w] * x[co,ci,h,w]
#define NG     4
#define HW     81                    // 9*9
#define NELT   (512 * 512 * 81)      // 21,233,664 floats
#define N4     (NELT / 4)            // 5,308,416 float4
#define BLK    256
#define UNROLL 4
#define CHUNK  (BLK * UNROLL)        // 1024 float4 per block-iteration
#define NBI    (N4 / CHUNK)          // 5184 block-iterations, exact
#define NBLK   2048                  // 8 blocks/CU x 256 CU

typedef float vf4 __attribute__((ext_vector_type(4)));

__global__ __launch_bounds__(BLK) void gabor_mul_kernel(
    const float* __restrict__ x,
    const float* __restrict__ theta,
    const float* __restrict__ lam,
    float* __restrict__ out)
{
    // Transposed gabor table: gt[p] = {g0(p), g1(p), g2(p), g3(p)} -> ds_read_b128.
    __shared__ vf4 gt[HW];

    const float PI_F = 3.14159274101257324f;              // np.float32(np.pi)
    const float INV_2SIG2 = 1.0f / (2.0f * PI_F * PI_F);  // sigma = pi
    if (threadIdx.x < HW) {
        int p = threadIdx.x;
        int i = p / 9;
        int j = p - i * 9;
        float fy = (float)(i - 4);
        float fx = (float)(j - 4);
        // env is rotation-invariant: xr^2 + yr^2 = fx^2 + fy^2
        float env = expf(-(fx * fx + fy * fy) * INV_2SIG2);
        vf4 v;
#pragma unroll
        for (int gi = 0; gi < NG; ++gi) {
            float th = theta[gi];
            float l  = lam[gi];
            float xr = fx * cosf(th) + fy * sinf(th);
            v[gi] = env * cosf(2.0f * PI_F * xr * l);
        }
        gt[p] = v;
    }
    __syncthreads();

    const vf4* __restrict__ x4 = (const vf4*)x;
    vf4* __restrict__ o4 = (vf4*)out;

    // Grid-stride over 1024-float4 block-chunks; x4 index = bi*CHUNK + tid + k*BLK,
    // so every load/store instruction is a wave-contiguous 1 KB transaction.
    for (unsigned bi = blockIdx.x; bi < NBI; bi += NBLK) {
        unsigned t0 = bi * CHUNK + threadIdx.x;

        // 4 independent loads issued back-to-back: 4x the MLP of the previous
        // version (1 load/iter FIFO-queued behind 4 outstanding stores).
        vf4 xv0 = x4[t0 + 0 * BLK];
        vf4 xv1 = x4[t0 + 1 * BLK];
        vf4 xv2 = x4[t0 + 2 * BLK];
        vf4 xv3 = x4[t0 + 3 * BLK];

        unsigned e0 = (t0 * 4u) % 81u;   // magic-mul, no div unit

#pragma unroll
        for (int k = 0; k < UNROLL; ++k) {
            // (k*BLK*4) % 81 is compile-time: 0, 52, 23, 75
            unsigned pk = e0 + (unsigned)((k * BLK * 4) % 81);
            if (pk >= 81u) pk -= 81u;
            if (pk >= 81u) pk -= 81u;
            unsigned p0 = pk;
            unsigned p1 = p0 + 1u; if (p1 >= 81u) p1 -= 81u;
            unsigned p2 = p1 + 1u; if (p2 >= 81u) p2 -= 81u;
            unsigned p3 = p2 + 1u; if (p3 >= 81u) p3 -= 81u;

            vf4 q0 = gt[p0];
            vf4 q1 = gt[p1];
            vf4 q2 = gt[p2];
            vf4 q3 = gt[p3];

            vf4 xk = (k == 0) ? xv0 : (k == 1) ? xv1 : (k == 2) ? xv2 : xv3;
            unsigned ti = t0 + (unsigned)(k * BLK);

            // Register transpose: component g of each q.
            vf4 o0 = { xk.x * q0.x, xk.y * q1.x, xk.z * q2.x, xk.w * q3.x };
            vf4 o1 = { xk.x * q0.y, xk.y * q1.y, xk.z * q2.y, xk.w * q3.y };
            vf4 o2 = { xk.x * q0.z, xk.y * q1.z, xk.z * q2.z, xk.w * q3.z };
            vf4 o3 = { xk.x * q0.w, xk.y * q1.w, xk.z * q2.w, xk.w * q3.w };

            // Plain stores (reverted nt: the 6.4 TB/s fill kernel uses plain
            // stores; nt gave no win in round 1).
            o4[(size_t)0 * N4 + ti] = o0;
            o4[(size_t)1 * N4 + ti] = o1;
            o4[(size_t)2 * N4 + ti] = o2;
            o4[(size_t)3 * N4 + ti] = o3;
        }
    }
}

extern "C" void kernel_launch(void* const* d_in, const int* in_sizes, int n_in,
                              void* d_out, int out_size, void* d_ws, size_t ws_size,
                              hipStream_t stream) {
    const float* x     = (const float*)d_in[0];
    const float* theta = (const float*)d_in[1];
    const float* lam   = (const float*)d_in[2];
    float* out = (float*)d_out;

    gabor_mul_kernel<<<NBLK, BLK, 0, stream>>>(x, theta, lam, out);
}